// Round 10
// baseline (92.924 us; speedup 1.0000x reference)
//
#include <hip/hip_runtime.h>
#include <hip/hip_bf16.h>
#include <math.h>

#define S_ 64
#define B_ 128
#define H_ 768
#define A_ 768

typedef __bf16 bf16_t;
typedef __attribute__((ext_vector_type(8))) __bf16 bf16x8;
typedef __attribute__((ext_vector_type(4))) __bf16 bf16x4;
typedef __attribute__((ext_vector_type(2))) __bf16 bf16x2;
typedef __attribute__((ext_vector_type(4))) float f32x4;

#define TOPIC_N   98304      // 128*768
#define IMG_N   6291456      // 64*128*768

__device__ __forceinline__ bf16x8 pack8(float4 a, float4 b) {
    bf16x8 o;
    o[0]=(bf16_t)a.x; o[1]=(bf16_t)a.y; o[2]=(bf16_t)a.z; o[3]=(bf16_t)a.w;
    o[4]=(bf16_t)b.x; o[5]=(bf16_t)b.y; o[6]=(bf16_t)b.z; o[7]=(bf16_t)b.w;
    return o;
}

__device__ __forceinline__ void glds16b(const bf16_t* g, bf16_t* l) {
    __builtin_amdgcn_global_load_lds(
        (const __attribute__((address_space(1))) uint32_t*)g,
        (__attribute__((address_space(3))) uint32_t*)l, 16, 0, 0);
}

// ============================================================================
// FAST PATH
// ============================================================================

// ---- prep: [topic; image; text] f32 -> bf16, one linear pass ----
__global__ __launch_bounds__(256)
void convert_kernel(const float* __restrict__ topic, const float* __restrict__ image,
                    const float* __restrict__ text, bf16_t* __restrict__ out) {
    const int i = blockIdx.x * 256 + threadIdx.x;      // 8 elems each
    const int T8 = TOPIC_N / 8, I8 = IMG_N / 8;
    const size_t e = (size_t)i * 8;
    const float* src; size_t off;
    if (i < T8)           { src = topic; off = e; }
    else if (i < T8 + I8) { src = image; off = e - TOPIC_N; }
    else                  { src = text;  off = e - TOPIC_N - IMG_N; }
    const float4* p = reinterpret_cast<const float4*>(src + off);
    float4 a = p[0], b = p[1];
    *reinterpret_cast<bf16x8*>(out + e) = pack8(a, b);
}

// ---- fused GEMM: BM=128 x BN=192, BK=64, 512 thr (8 waves, 2M x 4N).
//      W read f32 [k][n] directly from HBM (no transpose pass), reg-held
//      across the MFMA cluster, then cvt + transpose -> Bl[n][k].
//      B swizzle key = (n ^ (n>>3)) & 7 : conflict-free on BOTH the b32
//      writes (2-way) AND the b128 frag reads (8 distinct slots per 8-lane
//      group) -- r9's (n>>3)&7 key was read-side 8-way-conflicted (7.1M).
//      A bf16 via glds with XOR chunk swizzle (r8-proven). One s_barrier
//      per K-step. 80 KB LDS -> 2 blocks/CU; 24 MFMA/wave/K-step. ----
__global__ __launch_bounds__(512, 4)
void gemm_fused(const float* __restrict__ Wv, const float* __restrict__ Wq,
                const bf16_t* __restrict__ actB,
                const float* __restrict__ bq, const float* __restrict__ bv,
                bf16_t* __restrict__ Vws, float* __restrict__ Qws)
{
    __shared__ bf16_t Al[2][128 * 64];   // 16 KB each
    __shared__ bf16_t Bl[2][192 * 64];   // 24 KB each

    // XCD-chunked bijective remap, nwg = 772 (q=96, r=4) [T1/m204]
    const int b0 = blockIdx.x;
    const int xcd = b0 & 7, ii = b0 >> 3;
    const int bid = (xcd < 4) ? (xcd * 97 + ii) : (388 + (xcd - 4) * 96 + ii);

    const int tid = threadIdx.x;
    const bool isQ = (bid >= 768);
    int s, tm, tn;
    if (isQ) { s = S_; tm = 0; tn = bid - 768; }
    else     { s = bid / 12; const int t = bid % 12; tm = t / 4; tn = t % 4; }

    const bf16_t* Apanel;
    if (isQ || tm == 0) Apanel = actB;
    else if (tm == 1)   Apanel = actB + TOPIC_N + (size_t)s * B_ * H_;
    else                Apanel = actB + TOPIC_N + IMG_N + (size_t)s * B_ * H_;
    const float* Wbase = (isQ ? Wq : (Wv + (size_t)s * H_ * A_)) + tn * 192;

    const int wv = tid >> 6, lane = tid & 63;
    const int wr = wv >> 2, wc = wv & 3;          // wave tile: 64 rows x 48 cols
    const int fr = lane & 15, fg = lane >> 4;

    // W staging thread mapping: k-pair wk0 = 2*(tid>>4), n-groups 4*(tid&15)+64j
    const int wp  = tid >> 4;                      // 0..31
    const int wg  = tid & 15;
    const int wk0 = 2 * wp;

    f32x4 acc[4][3];
    #pragma unroll
    for (int i = 0; i < 4; ++i)
        #pragma unroll
        for (int j = 0; j < 3; ++j)
            acc[i][j] = (f32x4){0.f, 0.f, 0.f, 0.f};

    // A: 2 glds per thread, pre-swizzled source (r8 verbatim)
    auto stageA = [&](int t1, int buf) {
        const int k0 = t1 * 64;
        #pragma unroll
        for (int q = 0; q < 2; ++q) {
            const int slot = (q * 8 + wv) * 64 + lane;
            const int row = slot >> 3, c = slot & 7;
            glds16b(Apanel + (size_t)row * H_ + k0 + ((c ^ (row & 7)) * 8),
                    &Al[buf][(q * 8 + wv) * 512]);
        }
    };

    // W: 6 coalesced dwordx4 into regs (2 k-rows x 12 n's)
    f32x4 wreg[6];
    auto loadW = [&](int t1) {
        const float* base = Wbase + (size_t)(t1 * 64 + wk0) * A_;
        #pragma unroll
        for (int j = 0; j < 3; ++j) {
            wreg[2*j]   = *reinterpret_cast<const f32x4*>(base +        wg * 4 + 64 * j);
            wreg[2*j+1] = *reinterpret_cast<const f32x4*>(base + A_ +   wg * 4 + 64 * j);
        }
    };
    // cvt + in-reg transpose -> Bl[n][k]; key (n^(n>>3))&7, 2-way writes
    auto writeB = [&](int buf) {
        #pragma unroll
        for (int j = 0; j < 3; ++j)
            #pragma unroll
            for (int i = 0; i < 4; ++i) {
                const int n   = wg * 4 + 64 * j + i;
                const int key = (n ^ (n >> 3)) & 7;
                const int kx  = (((wk0 >> 3) ^ key) << 3) + (wk0 & 7);
                bf16x2 pr;
                pr[0] = (bf16_t)wreg[2*j][i];
                pr[1] = (bf16_t)wreg[2*j+1][i];
                *reinterpret_cast<bf16x2*>(&Bl[buf][n * 64 + kx]) = pr;
            }
    };

    // ---- prologue: tile 0 ----
    loadW(0);
    stageA(0, 0);
    writeB(0);                                   // auto vmcnt for wreg
    asm volatile("s_waitcnt vmcnt(0) lgkmcnt(0)" ::: "memory");
    __builtin_amdgcn_sched_barrier(0);
    __builtin_amdgcn_s_barrier();
    __builtin_amdgcn_sched_barrier(0);

    #pragma unroll
    for (int t = 0; t < 12; ++t) {
        const int cur = t & 1, nxt = cur ^ 1;
        if (t < 11) {
            loadW(t + 1);                        // oldest in vm queue
            stageA(t + 1, nxt);                  // newest (stays in flight longer)
        }
        __builtin_amdgcn_sched_barrier(0);       // pin loads above the compute

        #pragma unroll
        for (int kk = 0; kk < 2; ++kk) {
            bf16x8 af[4], bf_[3];
            const int kb = kk * 4 + fg;
            #pragma unroll
            for (int mi = 0; mi < 4; ++mi) {
                const int m = wr * 64 + mi * 16 + fr;
                af[mi] = *reinterpret_cast<const bf16x8*>(
                    &Al[cur][m * 64 + ((kb ^ (m & 7)) << 3)]);
            }
            #pragma unroll
            for (int ni = 0; ni < 3; ++ni) {
                const int n   = wc * 48 + ni * 16 + fr;
                const int key = (n ^ (n >> 3)) & 7;
                bf_[ni] = *reinterpret_cast<const bf16x8*>(
                    &Bl[cur][n * 64 + ((kb ^ key) << 3)]);
            }
            #pragma unroll
            for (int mi = 0; mi < 4; ++mi)
                #pragma unroll
                for (int ni = 0; ni < 3; ++ni)
                    acc[mi][ni] = __builtin_amdgcn_mfma_f32_16x16x32_bf16(
                        af[mi], bf_[ni], acc[mi][ni], 0, 0, 0);
        }
        __builtin_amdgcn_sched_barrier(0);

        if (t < 11) {
            writeB(nxt);                         // compiler waits vmcnt: W loads only
            asm volatile("s_waitcnt vmcnt(0) lgkmcnt(0)" ::: "memory");
            __builtin_amdgcn_sched_barrier(0);
            __builtin_amdgcn_s_barrier();
            __builtin_amdgcn_sched_barrier(0);
        }
    }

    // ---- epilogue: C/D map col = lane&15, row = (lane>>4)*4 + j ----
    if (isQ) {
        #pragma unroll
        for (int ni = 0; ni < 3; ++ni) {
            const int n = tn * 192 + wc * 48 + ni * 16 + fr;
            const float bias = bq[n];
            #pragma unroll
            for (int mi = 0; mi < 4; ++mi)
                #pragma unroll
                for (int j = 0; j < 4; ++j) {
                    const int m = wr * 64 + mi * 16 + fg * 4 + j;
                    Qws[(size_t)m * A_ + n] = acc[mi][ni][j] + bias;
                }
        }
    } else {
        const float* bvrow = bv + (size_t)s * A_;
        #pragma unroll
        for (int ni = 0; ni < 3; ++ni) {
            const int n = tn * 192 + wc * 48 + ni * 16 + fr;
            const float bias = bvrow[n];
            #pragma unroll
            for (int mi = 0; mi < 4; ++mi)
                #pragma unroll
                for (int j = 0; j < 4; ++j) {
                    const int b = wr * 64 + mi * 16 + fg * 4 + j;
                    Vws[(((size_t)s * B_ + b) * 3 + tm) * A_ + n] = (bf16_t)(acc[mi][ni][j] + bias);
                }
        }
    }
}

// ---- attention combine: one wave per (s,b) ----
__global__ __launch_bounds__(256)
void mm_attn_kernel(const bf16_t* __restrict__ Vws,
                    const float* __restrict__ Qws,
                    float* __restrict__ out)
{
    const int wave = threadIdx.x >> 6;
    const int lane = threadIdx.x & 63;
    const int p = blockIdx.x * 4 + wave;
    const int s = p >> 7;
    const int b = p & 127;
    const float*  qrow  = Qws + (size_t)b * A_;
    const bf16_t* vbase = Vws + ((size_t)s * B_ + b) * 3 * A_;

    float4 qv[3];
    bf16x4 vv[3][3];
    float p0 = 0.f, p1 = 0.f, p2 = 0.f;
    #pragma unroll
    for (int j = 0; j < 3; ++j) {
        const int a = lane * 4 + j * 256;
        qv[j]    = *reinterpret_cast<const float4*>(qrow + a);
        vv[0][j] = *reinterpret_cast<const bf16x4*>(vbase + 0*A_ + a);
        vv[1][j] = *reinterpret_cast<const bf16x4*>(vbase + 1*A_ + a);
        vv[2][j] = *reinterpret_cast<const bf16x4*>(vbase + 2*A_ + a);
        p0 += qv[j].x*(float)vv[0][j][0] + qv[j].y*(float)vv[0][j][1]
            + qv[j].z*(float)vv[0][j][2] + qv[j].w*(float)vv[0][j][3];
        p1 += qv[j].x*(float)vv[1][j][0] + qv[j].y*(float)vv[1][j][1]
            + qv[j].z*(float)vv[1][j][2] + qv[j].w*(float)vv[1][j][3];
        p2 += qv[j].x*(float)vv[2][j][0] + qv[j].y*(float)vv[2][j][1]
            + qv[j].z*(float)vv[2][j][2] + qv[j].w*(float)vv[2][j][3];
    }
    #pragma unroll
    for (int d = 1; d < 64; d <<= 1) {
        p0 += __shfl_xor(p0, d);
        p1 += __shfl_xor(p1, d);
        p2 += __shfl_xor(p2, d);
    }
    const float norm = 0.03608439182435161f;   // 1/sqrt(768)
    const float s0 = p0 * norm, s1 = p1 * norm, s2 = p2 * norm;
    const float mx = fmaxf(s0, fmaxf(s1, s2));
    const float e0 = expf(s0 - mx), e1 = expf(s1 - mx), e2 = expf(s2 - mx);
    const float inv = 1.f / (e0 + e1 + e2);
    const float a0 = e0 * inv, a1 = e1 * inv, a2 = e2 * inv;

    float* orow = out + ((size_t)s * B_ + b) * A_;
    #pragma unroll
    for (int j = 0; j < 3; ++j) {
        const int a = lane * 4 + j * 256;
        float4 o;
        o.x = a0*(float)vv[0][j][0] + a1*(float)vv[1][j][0] + a2*(float)vv[2][j][0];
        o.y = a0*(float)vv[0][j][1] + a1*(float)vv[1][j][1] + a2*(float)vv[2][j][1];
        o.z = a0*(float)vv[0][j][2] + a1*(float)vv[1][j][2] + a2*(float)vv[2][j][2];
        o.w = a0*(float)vv[0][j][3] + a1*(float)vv[1][j][3] + a2*(float)vv[2][j][3];
        *reinterpret_cast<float4*>(orow + a) = o;
    }
}

// ============================================================================
// FALLBACK PATH (round-1 GEMM, used only if ws_size is too small)
// ============================================================================
#define LDSPAD 40
__global__ __launch_bounds__(256, 2)
void mm_gemm_kernel(const float* __restrict__ topic,
                    const float* __restrict__ image,
                    const float* __restrict__ text,
                    const float* __restrict__ Wq,
                    const float* __restrict__ bq,
                    const float* __restrict__ Wv,
                    const float* __restrict__ bv,
                    bf16_t* __restrict__ Vws,
                    float*  __restrict__ Qws)
{
    __shared__ bf16_t Alds[128][LDSPAD];
    __shared__ bf16_t Blds[128][LDSPAD];

    const int bid = blockIdx.x;
    const int tid = threadIdx.x;
    const bool isQ = (bid >= S_ * 18);
    int s, tm, tn;
    if (isQ) { s = 0; tm = 0; tn = bid - S_ * 18; }
    else     { s = bid / 18; const int t = bid % 18; tm = t / 6; tn = t % 6; }

    const int ar  = tid >> 1;
    const int aks = (tid & 1) * 16;
    const float* arow;
    if (isQ) {
        arow = topic + (size_t)ar * H_;
    } else {
        const int am  = tm * 128 + ar;
        const int sel = am >> 7;
        const int b   = am & 127;
        if (sel == 0)      arow = topic + (size_t)b * H_;
        else if (sel == 1) arow = image + ((size_t)s * B_ + b) * H_;
        else               arow = text  + ((size_t)s * B_ + b) * H_;
    }
    const int arot = (ar >> 3) & 3;

    const int bn  = tid & 127;
    const int bks = (tid >> 7) * 16;
    const float* wbase = isQ ? Wq : (Wv + (size_t)s * H_ * A_);
    const float* bcolp = wbase + (size_t)(tn * 128 + bn);
    const int brot = (bn >> 3) & 3;

    const int wave = tid >> 6;
    const int lane = tid & 63;
    const int wr = wave >> 1;
    const int wc = wave & 1;
    const int fr = lane & 15;
    const int fg = lane >> 4;

    f32x4 acc[4][4];
    #pragma unroll
    for (int i = 0; i < 4; ++i)
        #pragma unroll
        for (int j = 0; j < 4; ++j)
            acc[i][j] = (f32x4){0.f, 0.f, 0.f, 0.f};

    for (int k0 = 0; k0 < H_; k0 += 32) {
        float4 av[4];
        const float4* ap = reinterpret_cast<const float4*>(arow + k0 + aks);
        #pragma unroll
        for (int i = 0; i < 4; ++i) av[i] = ap[i];
        float bvr[16];
        #pragma unroll
        for (int j = 0; j < 16; ++j) bvr[j] = bcolp[(size_t)(k0 + bks + j) * A_];

        __syncthreads();

        #pragma unroll
        for (int i = 0; i < 4; ++i) {
            const int j = (i + arot) & 3;
            bf16x4 c;
            c[0] = (bf16_t)av[j].x; c[1] = (bf16_t)av[j].y;
            c[2] = (bf16_t)av[j].z; c[3] = (bf16_t)av[j].w;
            *reinterpret_cast<bf16x4*>(&Alds[ar][aks + 4*j]) = c;
        }
        #pragma unroll
        for (int i = 0; i < 4; ++i) {
            const int j = (i + brot) & 3;
            bf16x4 c;
            c[0] = (bf16_t)bvr[4*j+0]; c[1] = (bf16_t)bvr[4*j+1];
            c[2] = (bf16_t)bvr[4*j+2]; c[3] = (bf16_t)bvr[4*j+3];
            *reinterpret_cast<bf16x4*>(&Blds[bn][bks + 4*j]) = c;
        }
        __syncthreads();

        bf16x8 afrag[4], bfrag[4];
        #pragma unroll
        for (int mi = 0; mi < 4; ++mi)
            afrag[mi] = *reinterpret_cast<const bf16x8*>(&Alds[wr*64 + mi*16 + fr][fg*8]);
        #pragma unroll
        for (int ni = 0; ni < 4; ++ni)
            bfrag[ni] = *reinterpret_cast<const bf16x8*>(&Blds[wc*64 + ni*16 + fr][fg*8]);
        #pragma unroll
        for (int mi = 0; mi < 4; ++mi)
            #pragma unroll
            for (int ni = 0; ni < 4; ++ni)
                acc[mi][ni] = __builtin_amdgcn_mfma_f32_16x16x32_bf16(
                    afrag[mi], bfrag[ni], acc[mi][ni], 0, 0, 0);
    }

    if (isQ) {
        #pragma unroll
        for (int ni = 0; ni < 4; ++ni) {
            const int n = tn*128 + wc*64 + ni*16 + fr;
            const float bias = bq[n];
            #pragma unroll
            for (int mi = 0; mi < 4; ++mi)
                #pragma unroll
                for (int j = 0; j < 4; ++j) {
                    const int m = wr*64 + mi*16 + fg*4 + j;
                    Qws[(size_t)m * A_ + n] = acc[mi][ni][j] + bias;
                }
        }
    } else {
        const float* bvrow = bv + (size_t)s * A_;
        #pragma unroll
        for (int ni = 0; ni < 4; ++ni) {
            const int n = tn*128 + wc*64 + ni*16 + fr;
            const float bias = bvrow[n];
            #pragma unroll
            for (int mi = 0; mi < 4; ++mi)
                #pragma unroll
                for (int j = 0; j < 4; ++j) {
                    const int b = wr*64 + mi*16 + fg*4 + j;
                    Vws[(((size_t)s * B_ + b) * 3 + tm) * A_ + n] = (bf16_t)(acc[mi][ni][j] + bias);
                }
        }
    }
}

// ============================================================================
extern "C" void kernel_launch(void* const* d_in, const int* in_sizes, int n_in,
                              void* d_out, int out_size, void* d_ws, size_t ws_size,
                              hipStream_t stream)
{
    const float* topic = (const float*)d_in[0];
    const float* image = (const float*)d_in[1];
    const float* text  = (const float*)d_in[2];
    const float* Wq    = (const float*)d_in[3];
    const float* bq    = (const float*)d_in[4];
    const float* Wv    = (const float*)d_in[5];
    const float* bv    = (const float*)d_in[6];
    float* out = (float*)d_out;

    const size_t szAct = (size_t)(TOPIC_N + 2 * IMG_N) * sizeof(bf16_t);  // 25,362,432
    const size_t szV   = (size_t)S_ * B_ * 3 * A_ * sizeof(bf16_t);       // 37,748,736
    const size_t szQ   = (size_t)B_ * A_ * sizeof(float);                 //    393,216
    const size_t need  = szAct + szV + szQ;                               // ~63.5 MB

    if (ws_size >= need) {
        char* w = (char*)d_ws;
        bf16_t* actB = (bf16_t*)w;  w += szAct;
        bf16_t* Vws  = (bf16_t*)w;  w += szV;
        float*  Qws  = (float*) w;

        convert_kernel<<<(TOPIC_N + 2 * IMG_N) / 8 / 256, 256, 0, stream>>>(topic, image, text, actB);
        gemm_fused<<<772, 512, 0, stream>>>(Wv, Wq, actB, bq, bv, Vws, Qws);
        mm_attn_kernel<<<S_ * B_ / 4, 256, 0, stream>>>(Vws, Qws, out);
    } else {
        bf16_t* Vws = (bf16_t*)d_ws;
        float*  Qws = (float*)((char*)d_ws + szV);
        mm_gemm_kernel<<<S_ * 18 + 6, 256, 0, stream>>>(topic, image, text, Wq, bq, Wv, bv, Vws, Qws);
        mm_attn_kernel<<<S_ * B_ / 4, 256, 0, stream>>>(Vws, Qws, out);
    }
}